// Round 3
// baseline (764.148 us; speedup 1.0000x reference)
//
#include <hip/hip_runtime.h>
#include <stdint.h>

// ---------------------------------------------------------------------------
// BiGRU + LayerNorm for MI355X (gfx950)
// kx: X fp32 -> bf16 (padded K 968->992), once
// k0: convert/scale weights to bf16 (log2e folded in; n-gate gets 2*log2e)
// k1: xp = x @ W_ih^T + b_ih  (m97-style: global_load_lds x16B both operands)
// k2: serial GRU scan, 8 WGs; no GIl (direct dist-2 reg prefetch of gi);
//     clobber-free lgkm-only barrier; gi+bias folded into MFMA C-init;
//     paired-rcp sigmoids + packed-f32 gate math
// k3: LayerNorm (unbiased std, clamp 1e-6), in place on d_out
// ---------------------------------------------------------------------------

#define LOG2E 1.4426950408889634f
#define TT 512
#define D_IN 968
#define KP 992
#define NOUT 768
#define HID 128

typedef __attribute__((ext_vector_type(8))) short short8;
typedef __attribute__((ext_vector_type(4))) float f32x4;
typedef __attribute__((ext_vector_type(2))) float f32x2;
typedef __attribute__((ext_vector_type(4))) unsigned int u32x4;
typedef __attribute__((ext_vector_type(2))) unsigned int u32x2;

__device__ __forceinline__ unsigned short f2bf(float f) {
  unsigned u = __builtin_bit_cast(unsigned, f);
  u += 0x7FFFu + ((u >> 16) & 1u);   // RTNE
  return (unsigned short)(u >> 16);
}
__device__ __forceinline__ unsigned pack2bf(float a, float b) {
  return (unsigned)f2bf(a) | ((unsigned)f2bf(b) << 16);
}
__device__ __forceinline__ float exp2_(float x) { return __builtin_amdgcn_exp2f(x); }
__device__ __forceinline__ float rcp_(float x)  { return __builtin_amdgcn_rcpf(x); }

__device__ __forceinline__ void async_load16(const void* g, void* l) {
  __builtin_amdgcn_global_load_lds(
      (const __attribute__((address_space(1))) unsigned int*)g,
      (__attribute__((address_space(3))) unsigned int*)l, 16, 0, 0);
}

// Workgroup barrier with LDS-only visibility: NO memory clobber so the
// waitcnt pass does not drain vmcnt (gi prefetch + OUT stores stay in
// flight). Volatile asm still gets barrier edges in the machine scheduler
// (unmodeled side effects => global memory object), so LDS ops can't cross.
__device__ __forceinline__ void bar_lds() {
  asm volatile("s_waitcnt lgkmcnt(0)\n\ts_barrier");
}

// ws layout
#define WIH_BYTES (NOUT * KP * 2)            // 1,523,712
#define WHH_BYTES (NOUT * HID * 2)           // 196,608
#define BIAS_BYTES 3072
#define BASE_OFF (WIH_BYTES + WHH_BYTES + BIAS_BYTES)  // 1,723,392 (256-aligned)
#define XBF_BYTES ((size_t)32768 * KP * 2)   // 65,011,712
#define XP_BYTES ((size_t)32768 * NOUT * 4)  // 100,663,296

// ---------------------------------------------------------------- kx: X->bf16
__global__ __launch_bounds__(256) void kx_convert(const float* __restrict__ X,
                                                  unsigned short* __restrict__ Xb) {
  const long row = blockIdx.x;
  const int t = threadIdx.x;
  if (t < 242) {
    f32x4 v = *(const f32x4*)(X + row * D_IN + t * 4);
    u32x2 p = {pack2bf(v.x, v.y), pack2bf(v.z, v.w)};
    *(u32x2*)(Xb + row * KP + t * 4) = p;
  } else if (t < 248) {
    *(u32x2*)(Xb + row * KP + t * 4) = (u32x2){0, 0};
  }
}

// ---------------------------------------------------------------- K0 convert
__global__ __launch_bounds__(256) void k0_convert(
    const float* __restrict__ wihf, const float* __restrict__ whhf,
    const float* __restrict__ bihf, const float* __restrict__ wihb,
    const float* __restrict__ whhb, const float* __restrict__ bihb,
    unsigned short* __restrict__ wih16, unsigned short* __restrict__ whh16,
    float* __restrict__ bias_s) {
  int blk = blockIdx.x, tid = threadIdx.x;
  if (blk < NOUT) {
    int n = blk;
    float sc = ((n % 384) < 256) ? LOG2E : 2.0f * LOG2E;
    const float* src = (n < 384) ? (wihf + (long)n * D_IN) : (wihb + (long)(n - 384) * D_IN);
    for (int c = 0; c < 4; c++) {
      int k = c * 256 + tid;
      if (k < KP) {
        float v = (k < D_IN) ? src[k] * sc : 0.0f;
        wih16[(long)n * KP + k] = f2bf(v);
      }
    }
  } else if (blk < NOUT + 96) {
    int e0 = ((blk - NOUT) * 256 + tid) * 4;
    for (int i = 0; i < 4; i++) {
      int e = e0 + i;
      int m = e >> 7, k = e & 127;
      float sc = ((m % 384) < 256) ? LOG2E : 2.0f * LOG2E;
      float v = (m < 384) ? whhf[m * HID + k] : whhb[(m - 384) * HID + k];
      whh16[e] = f2bf(v * sc);
    }
  } else {
    for (int c = 0; c < 3; c++) {
      int n = c * 256 + tid;
      if (n < NOUT) {
        float sc = ((n % 384) < 256) ? LOG2E : 2.0f * LOG2E;
        bias_s[n] = ((n < 384) ? bihf[n] : bihb[n - 384]) * sc;
      }
    }
  }
}

// ---------------------------------------------------------------- K1 fast GEMM
__global__ __launch_bounds__(256, 2) void k1_gemm_fast(
    const unsigned short* __restrict__ Xb, const unsigned short* __restrict__ W,
    const float* __restrict__ bias_s, float* __restrict__ XP) {
  __shared__ unsigned short As[128 * 32];
  __shared__ unsigned short Bs[128 * 32];

  const int tid = threadIdx.x;
  const int lane = tid & 63, w = tid >> 6;
  const int q = lane >> 4, l15 = lane & 15;
  const int wr = w >> 1, wc = w & 1;
  const int nt = blockIdx.x;   // 0..5 fast -> consecutive WGs share A-tile (L2)
  const int mt = blockIdx.y;   // 0..255
  const long R0 = (long)mt * 128;
  const int C0 = nt * 128;

  f32x4 acc[4][4];
#pragma unroll
  for (int i = 0; i < 4; i++)
#pragma unroll
    for (int j = 0; j < 4; j++) acc[i][j] = {0.f, 0.f, 0.f, 0.f};

  for (int it = 0; it < 31; it++) {
    const int k0 = it * 32;
#pragma unroll
    for (int c = 0; c < 2; c++) {
      int idx = c * 256 + w * 64 + lane;
      int row = idx >> 2, koff = (idx & 3) * 8;
      async_load16(Xb + (R0 + row) * KP + k0 + koff,
                   ((char*)As) + (c * 256 + w * 64) * 16);
      async_load16(W + (long)(C0 + row) * KP + k0 + koff,
                   ((char*)Bs) + (c * 256 + w * 64) * 16);
    }
    __syncthreads();
    short8 af[4], bf[4];
#pragma unroll
    for (int i = 0; i < 4; i++)
      af[i] = *(const short8*)&As[(wr * 64 + i * 16 + l15) * 32 + q * 8];
#pragma unroll
    for (int j = 0; j < 4; j++)
      bf[j] = *(const short8*)&Bs[(wc * 64 + j * 16 + l15) * 32 + q * 8];
#pragma unroll
    for (int i = 0; i < 4; i++)
#pragma unroll
      for (int j = 0; j < 4; j++)
        acc[i][j] = __builtin_amdgcn_mfma_f32_16x16x32_bf16(af[i], bf[j], acc[i][j], 0, 0, 0);
    __syncthreads();
  }
  float bv[4];
#pragma unroll
  for (int j = 0; j < 4; j++) bv[j] = bias_s[C0 + wc * 64 + j * 16 + l15];
#pragma unroll
  for (int i = 0; i < 4; i++)
#pragma unroll
    for (int j = 0; j < 4; j++) {
      int col = C0 + wc * 64 + j * 16 + l15;
      long Rb = R0 + wr * 64 + i * 16 + q * 4;
#pragma unroll
      for (int r = 0; r < 4; r++)
        XP[(Rb + r) * NOUT + col] = acc[i][j][r] + bv[j];
    }
}

// ---------------------------------------------------------------- K1 slow GEMM
#define AS_STRIDE 40
__global__ __launch_bounds__(256, 2) void k1_gemm_slow(
    const float* __restrict__ X, const unsigned short* __restrict__ W,
    const float* __restrict__ bias_s, float* __restrict__ XP) {
  __shared__ unsigned short As[128 * AS_STRIDE];
  __shared__ unsigned short Bs[128 * 32];
  const int tid = threadIdx.x;
  const int lane = tid & 63, w = tid >> 6;
  const int q = lane >> 4, l15 = lane & 15;
  const int wr = w >> 1, wc = w & 1;
  const int nt = blockIdx.x, mt = blockIdx.y;
  const long R0 = (long)mt * 128;
  const int C0 = nt * 128;
  const int ar = tid >> 1, ahf = tid & 1;
  f32x4 acc[4][4];
#pragma unroll
  for (int i = 0; i < 4; i++)
#pragma unroll
    for (int j = 0; j < 4; j++) acc[i][j] = {0.f, 0.f, 0.f, 0.f};
  const float* arow = X + (R0 + ar) * D_IN;
  for (int it = 0; it < 31; it++) {
    int k0 = it * 32;
    unsigned pk[8];
#pragma unroll
    for (int c = 0; c < 4; c++) {
      int kc = k0 + ahf * 16 + c * 4;
      kc = (kc <= 964) ? kc : 964;
      f32x4 v = *(const f32x4*)(arow + kc);
      pk[c * 2 + 0] = pack2bf(v.x, v.y);
      pk[c * 2 + 1] = pack2bf(v.z, v.w);
    }
    unsigned short* adst = &As[ar * AS_STRIDE + ahf * 16];
    *(u32x4*)adst = (u32x4){pk[0], pk[1], pk[2], pk[3]};
    *(u32x4*)(adst + 8) = (u32x4){pk[4], pk[5], pk[6], pk[7]};
#pragma unroll
    for (int c = 0; c < 2; c++) {
      int idx = c * 256 + w * 64 + lane;
      int brow = idx >> 2, koff = (idx & 3) * 8;
      async_load16(W + (long)(C0 + brow) * KP + k0 + koff,
                   ((char*)Bs) + (c * 256 + w * 64) * 16);
    }
    __syncthreads();
    short8 af[4], bf[4];
#pragma unroll
    for (int i = 0; i < 4; i++)
      af[i] = *(const short8*)&As[(wr * 64 + i * 16 + l15) * AS_STRIDE + q * 8];
#pragma unroll
    for (int j = 0; j < 4; j++)
      bf[j] = *(const short8*)&Bs[(wc * 64 + j * 16 + l15) * 32 + q * 8];
#pragma unroll
    for (int i = 0; i < 4; i++)
#pragma unroll
      for (int j = 0; j < 4; j++)
        acc[i][j] = __builtin_amdgcn_mfma_f32_16x16x32_bf16(af[i], bf[j], acc[i][j], 0, 0, 0);
    __syncthreads();
  }
  float bv[4];
#pragma unroll
  for (int j = 0; j < 4; j++) bv[j] = bias_s[C0 + wc * 64 + j * 16 + l15];
#pragma unroll
  for (int i = 0; i < 4; i++)
#pragma unroll
    for (int j = 0; j < 4; j++) {
      int col = C0 + wc * 64 + j * 16 + l15;
      long Rb = R0 + wr * 64 + i * 16 + q * 4;
#pragma unroll
      for (int r = 0; r < 4; r++)
        XP[(Rb + r) * NOUT + col] = acc[i][j][r] + bv[j];
    }
}

// ---------------------------------------------------------------- K2 GRU scan
__global__ __launch_bounds__(512) void k2_gru(
    const unsigned short* __restrict__ WHH, const float* __restrict__ XP,
    const float* __restrict__ bhh_f, const float* __restrict__ bhh_b,
    float* __restrict__ OUT) {
  __shared__ unsigned short Hl[2][16 * 128];  // double-buffered H (bf16, swizzled)

  const int tid = threadIdx.x;
  const int lane = tid & 63, w = tid >> 6;  // wave w owns cols [16w,16w+16)
  const int q = lane >> 4, b = lane & 15;
  const int dir = blockIdx.x & 1, bg = blockIdx.x >> 1;
  const int j0 = w * 16 + q * 4;

  for (int i = tid; i < 2 * 16 * 128; i += 512) ((unsigned short*)Hl)[i] = 0;

  // resident Whh A-fragments
  short8 afr[3][4];
#pragma unroll
  for (int g = 0; g < 3; g++)
#pragma unroll
    for (int kt = 0; kt < 4; kt++) {
      int row = dir * 384 + g * 128 + w * 16 + b;
      afr[g][kt] = *(const short8*)(WHH + (long)row * HID + kt * 32 + q * 8);
    }
  const float* bhh = dir ? bhh_b : bhh_f;
  f32x4 bh[3];
#pragma unroll
  for (int g = 0; g < 3; g++) {
    f32x4 t = *(const f32x4*)(bhh + g * 128 + j0);
    bh[g] = t * ((g < 2) ? LOG2E : 2.0f * LOG2E);
  }

  // gi in CONSUMER layout: lane(q,b) loads its own 3x f32x4 per step.
  // Per (b,g): the 4 quads' 16B chunks tile one 64B line -> fully coalesced.
  const float* gi_ptr = XP + (long)(bg * 16 + b) * TT * NOUT + dir * 384 + w * 16 + q * 4;
  const long out_base = (long)(bg * 16 + b) * TT * 256 + dir * 128 + j0;

  // dist-2 prefetch register sets (static-indexed via unroll-2)
  f32x4 gp[2][3];
  {
    const int td0 = dir ? (TT - 1) : 0;
    const int td1 = dir ? (TT - 2) : 1;
    const float* p0 = gi_ptr + (long)td0 * NOUT;
    const float* p1 = gi_ptr + (long)td1 * NOUT;
#pragma unroll
    for (int g = 0; g < 3; g++) gp[0][g] = *(const f32x4*)(p0 + g * 128);
#pragma unroll
    for (int g = 0; g < 3; g++) gp[1][g] = *(const f32x4*)(p1 + g * 128);
  }
  f32x4 h = {0.f, 0.f, 0.f, 0.f};
  __syncthreads();

  for (int tb = 0; tb < TT; tb += 2) {
#pragma unroll
    for (int u = 0; u < 2; u++) {
      const int t = tb + u;
      const int cur = u, nxt = u ^ 1;   // t&1 == u
      const int td = dir ? (TT - 1 - t) : t;

      // 1) H B-fragments from Hl[cur] (swizzled chunks)
      short8 bfr[4];
#pragma unroll
      for (int kt = 0; kt < 4; kt++) {
        int ch = ((kt * 4 + q) ^ (b & 7)) * 8;
        bfr[kt] = *(const short8*)&Hl[cur][b * 128 + ch];
      }
      // 2) C-init: fold gi + bias for r/z; bias only for n (r multiplies gh_n)
      f32x4 accR = gp[u][0] + bh[0];
      f32x4 accZ = gp[u][1] + bh[1];
      f32x4 gn = gp[u][2];
      f32x4 accN = bh[2];
      // 3) refill gp[u] with gi(t+2)  (consumed 2 steps from now)
      {
        const int t2 = (t + 2 < TT) ? t + 2 : TT - 1;
        const int td2 = dir ? (TT - 1 - t2) : t2;
        const float* p2 = gi_ptr + (long)td2 * NOUT;
        gp[u][0] = *(const f32x4*)(p2);
        gp[u][1] = *(const f32x4*)(p2 + 128);
        gp[u][2] = *(const f32x4*)(p2 + 256);
      }
      // 4) MFMA: 3 independent chains of 4
#pragma unroll
      for (int kt = 0; kt < 4; kt++) {
        accR = __builtin_amdgcn_mfma_f32_16x16x32_bf16(afr[0][kt], bfr[kt], accR, 0, 0, 0);
        accZ = __builtin_amdgcn_mfma_f32_16x16x32_bf16(afr[1][kt], bfr[kt], accZ, 0, 0, 0);
        accN = __builtin_amdgcn_mfma_f32_16x16x32_bf16(afr[2][kt], bfr[kt], accN, 0, 0, 0);
      }
      // 5) gate math: packed f32 pairs, paired rcp for r/z
      f32x4 hnew;
#pragma unroll
      for (int p = 0; p < 2; p++) {
        f32x2 pr = {accR[2 * p], accR[2 * p + 1]};
        f32x2 pz = {accZ[2 * p], accZ[2 * p + 1]};
        f32x2 an = {accN[2 * p], accN[2 * p + 1]};
        f32x2 gn2 = {gn[2 * p], gn[2 * p + 1]};
        f32x2 h2 = {h[2 * p], h[2 * p + 1]};
        f32x2 ea = {exp2_(-pr.x), exp2_(-pr.y)};
        f32x2 eb = {exp2_(-pz.x), exp2_(-pz.y)};
        f32x2 A = ea + 1.0f;
        f32x2 B = eb + 1.0f;
        f32x2 P = A * B;
        f32x2 ip = {rcp_(P.x), rcp_(P.y)};
        f32x2 r = ip * B;
        f32x2 z = ip * A;
        f32x2 pn = gn2 + r * an;
        f32x2 E = {exp2_(pn.x), exp2_(pn.y)};
        f32x2 Dn = E + 1.0f;
        f32x2 iD = {rcp_(Dn.x), rcp_(Dn.y)};
        f32x2 n = 1.0f - 2.0f * iD;
        f32x2 hn = n + z * (h2 - n);
        hnew[2 * p] = hn.x;
        hnew[2 * p + 1] = hn.y;
      }
      h = hnew;
      // 6) h' -> Hl[nxt] (bf16, swizzled) and global OUT (fp32)
      {
        int ch = ((j0 >> 3) ^ (b & 7)) * 8 + (j0 & 7);
        u32x2 hv = {pack2bf(hnew[0], hnew[1]), pack2bf(hnew[2], hnew[3])};
        *(u32x2*)&Hl[nxt][b * 128 + ch] = hv;
      }
      *(f32x4*)(OUT + out_base + (long)td * 256) = hnew;
      // 7) LDS-only barrier; gi prefetch + OUT store stay in flight
      bar_lds();
    }
  }
}

// ---------------------------------------------------------------- K3 LayerNorm
__global__ __launch_bounds__(256) void k3_ln(float* __restrict__ OUT,
                                             const float* __restrict__ lnw,
                                             const float* __restrict__ lnb) {
  const int tid = threadIdx.x, lane = tid & 63, w = tid >> 6;
  const long row = (long)blockIdx.x * 4 + w;
  float* p = OUT + row * 256 + lane * 4;
  f32x4 x = *(const f32x4*)p;
  float s = x[0] + x[1] + x[2] + x[3];
  float s2 = x[0] * x[0] + x[1] * x[1] + x[2] * x[2] + x[3] * x[3];
#pragma unroll
  for (int m = 1; m < 64; m <<= 1) {
    s += __shfl_xor(s, m, 64);
    s2 += __shfl_xor(s2, m, 64);
  }
  float mu = s * (1.0f / 256.0f);
  float var = (s2 - s * mu) * (1.0f / 255.0f);  // ddof=1
  var = fmaxf(var, 0.0f);
  float sig = fmaxf(sqrtf(var), 1e-6f);
  float inv = 1.0f / sig;
  f32x4 wv = *(const f32x4*)(lnw + lane * 4);
  f32x4 bv = *(const f32x4*)(lnb + lane * 4);
  f32x4 y;
#pragma unroll
  for (int i = 0; i < 4; i++) y[i] = (x[i] - mu) * inv * wv[i] + bv[i];
  *(f32x4*)p = y;
}

// ---------------------------------------------------------------- launch
extern "C" void kernel_launch(void* const* d_in, const int* in_sizes, int n_in,
                              void* d_out, int out_size, void* d_ws, size_t ws_size,
                              hipStream_t stream) {
  const float* x = (const float*)d_in[0];
  const float* wihf = (const float*)d_in[1];
  const float* whhf = (const float*)d_in[2];
  const float* bihf = (const float*)d_in[3];
  const float* bhhf = (const float*)d_in[4];
  const float* wihb = (const float*)d_in[5];
  const float* whhb = (const float*)d_in[6];
  const float* bihb = (const float*)d_in[7];
  const float* bhhb = (const float*)d_in[8];
  const float* lnw = (const float*)d_in[9];
  const float* lnb = (const float*)d_in[10];

  char* ws = (char*)d_ws;
  unsigned short* wih16 = (unsigned short*)ws;
  unsigned short* whh16 = (unsigned short*)(ws + WIH_BYTES);
  float* bias_s = (float*)(ws + WIH_BYTES + WHH_BYTES);
  float* out = (float*)d_out;

  const size_t need_fast = (size_t)BASE_OFF + XBF_BYTES + XP_BYTES;  // ~167.4 MB

  hipLaunchKernelGGL(k0_convert, dim3(768 + 96 + 1), dim3(256), 0, stream,
                     wihf, whhf, bihf, wihb, whhb, bihb, wih16, whh16, bias_s);

  float* xp;
  if (ws_size >= need_fast) {
    unsigned short* xbf = (unsigned short*)(ws + BASE_OFF);
    xp = (float*)(ws + BASE_OFF + XBF_BYTES);
    hipLaunchKernelGGL(kx_convert, dim3(32768), dim3(256), 0, stream, x, xbf);
    hipLaunchKernelGGL(k1_gemm_fast, dim3(6, 256), dim3(256), 0, stream,
                       xbf, wih16, bias_s, xp);
  } else {
    xp = (float*)(ws + BASE_OFF);
    hipLaunchKernelGGL(k1_gemm_slow, dim3(6, 256), dim3(256), 0, stream,
                       x, wih16, bias_s, xp);
  }
  hipLaunchKernelGGL(k2_gru, dim3(8), dim3(512), 0, stream, whh16, xp, bhhf, bhhb, out);
  hipLaunchKernelGGL(k3_ln, dim3(8192), dim3(256), 0, stream, out, lnw, lnb);
}